// Round 13
// baseline (1339.188 us; speedup 1.0000x reference)
//
#include <hip/hip_runtime.h>
#include <math.h>

#define IGNORE_INDEX (-100)

typedef __attribute__((ext_vector_type(4))) int i32x4;
typedef __attribute__((ext_vector_type(4))) float f32x4;

static constexpr int B_ = 4, S_ = 2048, H_ = 4096, V_ = 32000;
static constexpr int N_ = B_ * (S_ - 1);      // 8188 rows after causal shift
static constexpr int NPAD = 8192;             // padded rows
static constexpr int BM = 256, BN = 256, BK = 64;
static constexpr int NVB = V_ / BN;           // 125 v-blocks
static constexpr int NRB = NPAD / BM;         // 32 row-blocks
static constexpr int NKT = H_ / BK;           // 64 K-tiles
static constexpr int NWG = NVB * NRB;         // 4000 blocks

__device__ __forceinline__ void gload16(const signed char* src, signed char* ldst) {
    __builtin_amdgcn_global_load_lds(
        (const __attribute__((address_space(1))) unsigned int*)src,
        (__attribute__((address_space(3))) unsigned int*)ldst, 16, 0, 0);
}

// ---------- per-row symmetric int8 quantization of hidden_states (causal-shifted, padded) ----------
__global__ void quant_hs_kernel(const float* __restrict__ hs,
                                signed char* __restrict__ qA, float* __restrict__ sA) {
    const int row = blockIdx.x;          // 0..NPAD-1
    const int tid = threadIdx.x;         // 256 threads
    __shared__ float red[256];
    f32x4 v0, v1, v2, v3;
    if (row < N_) {
        int b = row / (S_ - 1);
        int s = row - b * (S_ - 1);
        const float* src = hs + (size_t)(b * S_ + s) * H_;
        v0 = *(const f32x4*)(src + tid * 4 + 0 * 1024);
        v1 = *(const f32x4*)(src + tid * 4 + 1 * 1024);
        v2 = *(const f32x4*)(src + tid * 4 + 2 * 1024);
        v3 = *(const f32x4*)(src + tid * 4 + 3 * 1024);
    } else {
        v0 = v1 = v2 = v3 = (f32x4)0.f;
    }
    float amax = 0.f;
    amax = fmaxf(amax, fmaxf(fmaxf(fabsf(v0[0]), fabsf(v0[1])), fmaxf(fabsf(v0[2]), fabsf(v0[3]))));
    amax = fmaxf(amax, fmaxf(fmaxf(fabsf(v1[0]), fabsf(v1[1])), fmaxf(fabsf(v1[2]), fabsf(v1[3]))));
    amax = fmaxf(amax, fmaxf(fmaxf(fabsf(v2[0]), fabsf(v2[1])), fmaxf(fabsf(v2[2]), fabsf(v2[3]))));
    amax = fmaxf(amax, fmaxf(fmaxf(fabsf(v3[0]), fabsf(v3[1])), fmaxf(fabsf(v3[2]), fabsf(v3[3]))));
    red[tid] = amax;
    __syncthreads();
    for (int d = 128; d > 0; d >>= 1) {
        if (tid < d) red[tid] = fmaxf(red[tid], red[tid + d]);
        __syncthreads();
    }
    const float m = fmaxf(red[0], 1e-30f);
    const float inv = 127.f / m;
    unsigned int* dst = (unsigned int*)(qA + (size_t)row * H_);
#define QPACK(vv, J) do { \
    int q0 = __float2int_rn(vv[0] * inv), q1 = __float2int_rn(vv[1] * inv); \
    int q2 = __float2int_rn(vv[2] * inv), q3 = __float2int_rn(vv[3] * inv); \
    unsigned int p = (q0 & 255) | ((q1 & 255) << 8) | ((q2 & 255) << 16) | ((unsigned)(q3 & 255) << 24); \
    dst[tid + (J) * 256] = p; } while (0)
    QPACK(v0, 0); QPACK(v1, 1); QPACK(v2, 2); QPACK(v3, 3);
#undef QPACK
    if (tid == 0) sA[row] = m * (1.f / 127.f);
}

// ---------- per-row symmetric int8 quantization of lm_head weight ----------
__global__ void quant_w_kernel(const float* __restrict__ w,
                               signed char* __restrict__ qW, float* __restrict__ sW) {
    const int row = blockIdx.x;          // 0..V-1
    const int tid = threadIdx.x;
    __shared__ float red[256];
    const float* src = w + (size_t)row * H_;
    f32x4 v0 = *(const f32x4*)(src + tid * 4 + 0 * 1024);
    f32x4 v1 = *(const f32x4*)(src + tid * 4 + 1 * 1024);
    f32x4 v2 = *(const f32x4*)(src + tid * 4 + 2 * 1024);
    f32x4 v3 = *(const f32x4*)(src + tid * 4 + 3 * 1024);
    float amax = 0.f;
    amax = fmaxf(amax, fmaxf(fmaxf(fabsf(v0[0]), fabsf(v0[1])), fmaxf(fabsf(v0[2]), fabsf(v0[3]))));
    amax = fmaxf(amax, fmaxf(fmaxf(fabsf(v1[0]), fabsf(v1[1])), fmaxf(fabsf(v1[2]), fabsf(v1[3]))));
    amax = fmaxf(amax, fmaxf(fmaxf(fabsf(v2[0]), fabsf(v2[1])), fmaxf(fabsf(v2[2]), fabsf(v2[3]))));
    amax = fmaxf(amax, fmaxf(fmaxf(fabsf(v3[0]), fabsf(v3[1])), fmaxf(fabsf(v3[2]), fabsf(v3[3]))));
    red[tid] = amax;
    __syncthreads();
    for (int d = 128; d > 0; d >>= 1) {
        if (tid < d) red[tid] = fmaxf(red[tid], red[tid + d]);
        __syncthreads();
    }
    const float m = fmaxf(red[0], 1e-30f);
    const float inv = 127.f / m;
    unsigned int* dst = (unsigned int*)(qW + (size_t)row * H_);
#define QPACK(vv, J) do { \
    int q0 = __float2int_rn(vv[0] * inv), q1 = __float2int_rn(vv[1] * inv); \
    int q2 = __float2int_rn(vv[2] * inv), q3 = __float2int_rn(vv[3] * inv); \
    unsigned int p = (q0 & 255) | ((q1 & 255) << 8) | ((q2 & 255) << 16) | ((unsigned)(q3 & 255) << 24); \
    dst[tid + (J) * 256] = p; } while (0)
    QPACK(v0, 0); QPACK(v1, 1); QPACK(v2, 2); QPACK(v3, 3);
#undef QPACK
    if (tid == 0) sW[row] = m * (1.f / 127.f);
}

// ---------- 256x256 8-wave i8 GEMM: BK=64, 4-buf ring, fine phases + COUNTED vmcnt ----------
// The untested cell from R5/R7/R9: m201/m218's structure = fine 16-MFMA phases with
// barrier pairs (R7 had this) AND counted vmcnt that never drains to 0 in the loop
// (R5 had this, but with coarse phases).  Per tile (BK=64, NKT=64): 2 phases:
//   phase0: {2 A-gloads for tile T+2; 8 ds_reads (bv0-3, av0-3); bar; lgkm(0); SB;
//            setprio(1); 16 MFMA (m0-3); setprio(0); bar}
//   phase1: {2 B-gloads for T+2; 4 ds_reads (av4-7); bar; lgkm(0); SB; setprio(1);
//            16 MFMA (m4-7); setprio(0); vmcnt(4) [T+2's loads stay in flight]; bar}
// 4 LDS buffers (4 x 32 KB): T reading, T+1 landed, T+2 landing.  RAW: end-of-(T-1)
// vmcnt(4)+barrier guarantees T landed.  WAR: buffer (T+2)&3 last read at T-2, two
// barriers back.  LDS rows are 64 B: the R5-verified 0-conflict swizzle applies --
// phys = r*64 + ((lr*16) ^ (((r>>1)&3)<<4)) (row bit 0 is already in the bank index
// via the 64B stride); staging source inverse = q ^ (((q>>7)&3)<<4).
__global__ __launch_bounds__(512, 2) void gemm_lse_kernel(
        const signed char* __restrict__ Aq,    // [NPAD][H] i8
        const signed char* __restrict__ Wq,    // [V][H] i8
        const float* __restrict__ sA,          // [NPAD]
        const float* __restrict__ sW,          // [V]
        const int* __restrict__ labels,        // [B][S]
        float* __restrict__ partial_m,         // [NPAD][NVB]
        float* __restrict__ partial_s,         // [NPAD][NVB]
        float* __restrict__ label_logit)       // [NPAD]
{
    __shared__ signed char lds[4][2][BM * BK];   // [buf][A=0/B=1], 4 x 32 KiB = 128 KiB

    const int tid  = threadIdx.x;
    const int lane = tid & 63;
    const int wid  = tid >> 6;
    const int wr   = wid >> 2;      // 0..1: row half
    const int wc   = wid & 3;       // 0..3: col quarter
    const int lq   = lane & 15;
    const int lr   = lane >> 4;

    // bijective XCD swizzle (NWG % 8 == 0)
    int lin = blockIdx.x;
    int swz = (lin & 7) * (NWG / 8) + (lin >> 3);
    const int rb = swz / NVB;
    const int vb = swz - rb * NVB;

    const signed char* Abase = Aq + (size_t)rb * BM * H_;
    const signed char* Bbase = Wq + (size_t)vb * BN * H_;

    // ds_read physical byte offsets (64 B rows; R5-verified 0-conflict swizzle)
    int pA[8], pB[4];
    #pragma unroll
    for (int m = 0; m < 8; ++m) {
        int r = wr * 128 + m * 16 + lq;
        pA[m] = r * 64 + ((lr * 16) ^ (((r >> 1) & 3) << 4));
    }
    #pragma unroll
    for (int n = 0; n < 4; ++n) {
        int r = wc * 64 + n * 16 + lq;
        pB[n] = r * 64 + ((lr * 16) ^ (((r >> 1) & 3) << 4));
    }

    // staging: linear physical dest; inverse-swizzled per-lane global source.
    // 2 gloads per matrix per tile (16 KB tile / 512 threads / 16 B).
    int rowS[2], colS[2];
    #pragma unroll
    for (int i = 0; i < 2; ++i) {
        int q = i * 8192 + wid * 1024 + lane * 16;   // physical
        int b = q ^ (((q >> 7) & 3) << 4);           // logical
        rowS[i] = b >> 6;
        colS[i] = b & 63;                            // i8: byte == element
    }

    i32x4 acc[8][4] = {};

    // ---------- prologue: stage tiles 0 and 1 into bufs 0,1 ----------
    #pragma unroll
    for (int X = 0; X < 2; ++X) {
        signed char* dA = &lds[X][0][0];
        signed char* dB = &lds[X][1][0];
        const int k0 = X * BK;
        gload16(Abase + (size_t)rowS[0] * H_ + k0 + colS[0], dA + 0 * 8192 + wid * 1024);
        gload16(Abase + (size_t)rowS[1] * H_ + k0 + colS[1], dA + 1 * 8192 + wid * 1024);
        gload16(Bbase + (size_t)rowS[0] * H_ + k0 + colS[0], dB + 0 * 8192 + wid * 1024);
        gload16(Bbase + (size_t)rowS[1] * H_ + k0 + colS[1], dB + 1 * 8192 + wid * 1024);
    }
    asm volatile("s_waitcnt vmcnt(4)" ::: "memory");   // tile 0 landed; tile 1 in flight
    __builtin_amdgcn_s_barrier();

#define RDI(tile, off) (*(const i32x4*)((const char*)(tile) + (off)))
#define MF(af, bf, c4) __builtin_amdgcn_mfma_i32_16x16x64_i8(af, bf, c4, 0, 0, 0)
#define PHASE_MID() do { \
    __builtin_amdgcn_s_barrier(); \
    asm volatile("s_waitcnt lgkmcnt(0)" ::: "memory"); \
    __builtin_amdgcn_sched_barrier(0); \
    __builtin_amdgcn_s_setprio(1); } while (0)

    for (int T = 0; T < NKT; ++T) {
        const signed char* tA = &lds[T & 3][0][0];
        const signed char* tB = &lds[T & 3][1][0];
        signed char* dA = &lds[(T + 2) & 3][0][0];
        signed char* dB = &lds[(T + 2) & 3][1][0];
        const int kn = (T + 2) * BK;
        const bool pre = (T + 2 < NKT);
        i32x4 av[4], bv[4], aw[4];

        // ---- phase 0: stage A(T+2); read bv0-3 + av0-3; MFMA m0-3
        if (pre) {
            gload16(Abase + (size_t)rowS[0] * H_ + kn + colS[0], dA + 0 * 8192 + wid * 1024);
            gload16(Abase + (size_t)rowS[1] * H_ + kn + colS[1], dA + 1 * 8192 + wid * 1024);
        }
        #pragma unroll
        for (int n = 0; n < 4; ++n) bv[n] = RDI(tB, pB[n]);
        #pragma unroll
        for (int m = 0; m < 4; ++m) av[m] = RDI(tA, pA[m]);
        PHASE_MID();
        #pragma unroll
        for (int m = 0; m < 4; ++m)
            #pragma unroll
            for (int n = 0; n < 4; ++n)
                acc[m][n] = MF(av[m], bv[n], acc[m][n]);
        __builtin_amdgcn_s_setprio(0);
        __builtin_amdgcn_s_barrier();

        // ---- phase 1: stage B(T+2); read av4-7; MFMA m4-7; counted boundary wait
        if (pre) {
            gload16(Bbase + (size_t)rowS[0] * H_ + kn + colS[0], dB + 0 * 8192 + wid * 1024);
            gload16(Bbase + (size_t)rowS[1] * H_ + kn + colS[1], dB + 1 * 8192 + wid * 1024);
        }
        #pragma unroll
        for (int m = 0; m < 4; ++m) aw[m] = RDI(tA, pA[4 + m]);
        PHASE_MID();
        #pragma unroll
        for (int m = 0; m < 4; ++m)
            #pragma unroll
            for (int n = 0; n < 4; ++n)
                acc[4 + m][n] = MF(aw[m], bv[n], acc[4 + m][n]);
        __builtin_amdgcn_s_setprio(0);
        if (pre) {
            asm volatile("s_waitcnt vmcnt(4)" ::: "memory");   // T+1 landed; T+2 in flight
        } else if (T + 1 < NKT) {
            asm volatile("s_waitcnt vmcnt(0)" ::: "memory");   // epilogue drain
        }
        __builtin_amdgcn_s_barrier();
    }

    // ---------- epilogue: dequant + per-row max & sum-exp over this 256-col tile ----------
    __syncthreads();
    float* red_m = (float*)&lds[0][0][0];   // [4][256]
    float* red_s = red_m + 1024;            // [4][256]

    const float* sArow = sA + rb * 256 + wr * 128;
    const float sw0 = sW[vb * 256 + wc * 64 + 0 * 16 + lq];
    const float sw1 = sW[vb * 256 + wc * 64 + 1 * 16 + lq];
    const float sw2 = sW[vb * 256 + wc * 64 + 2 * 16 + lq];
    const float sw3 = sW[vb * 256 + wc * 64 + 3 * 16 + lq];

    #pragma unroll
    for (int m = 0; m < 8; ++m) {
        f32x4 sav = *(const f32x4*)(sArow + m * 16 + lr * 4);
        #pragma unroll
        for (int q = 0; q < 4; ++q) {
            const float sa = sav[q];
            float l0 = (float)acc[m][0][q] * sa * sw0;
            float l1 = (float)acc[m][1][q] * sa * sw1;
            float l2 = (float)acc[m][2][q] * sa * sw2;
            float l3 = (float)acc[m][3][q] * sa * sw3;
            float mx = fmaxf(fmaxf(l0, l1), fmaxf(l2, l3));
            #pragma unroll
            for (int d = 1; d < 16; d <<= 1) mx = fmaxf(mx, __shfl_xor(mx, d, 64));
            float ss = __expf(l0 - mx) + __expf(l1 - mx) + __expf(l2 - mx) + __expf(l3 - mx);
            #pragma unroll
            for (int d = 1; d < 16; d <<= 1) ss += __shfl_xor(ss, d, 64);
            if (lq == 0) {
                int rloc = wr * 128 + m * 16 + lr * 4 + q;
                red_m[wc * 256 + rloc] = mx;
                red_s[wc * 256 + rloc] = ss;
            }
            int rowg = rb * BM + wr * 128 + m * 16 + lr * 4 + q;
            if (rowg < N_) {
                int bb = rowg / (S_ - 1);
                int s = rowg - bb * (S_ - 1);
                int lbl = labels[bb * S_ + s + 1];
                int ccol = lbl - (vb * BN + wc * 64);
                if (ccol >= 0 && ccol < 64 && (ccol & 15) == lq) {
                    int nsel = ccol >> 4;
                    float val;
                    if (nsel == 0)      val = l0;
                    else if (nsel == 1) val = l1;
                    else if (nsel == 2) val = l2;
                    else                val = l3;
                    label_logit[rowg] = val;
                }
            }
        }
    }
    __syncthreads();
    if (tid < 256) {
        float m0 = red_m[tid], m1 = red_m[256 + tid], m2 = red_m[512 + tid], m3 = red_m[768 + tid];
        float s0 = red_s[tid], s1 = red_s[256 + tid], s2 = red_s[512 + tid], s3 = red_s[768 + tid];
        float mm = fmaxf(fmaxf(m0, m1), fmaxf(m2, m3));
        float ss = s0 * __expf(m0 - mm) + s1 * __expf(m1 - mm)
                 + s2 * __expf(m2 - mm) + s3 * __expf(m3 - mm);
        int rowg = rb * BM + tid;
        partial_m[(size_t)rowg * NVB + vb] = mm;
        partial_s[(size_t)rowg * NVB + vb] = ss;
    }
}

// ---------- per-row combine of partials -> nll ----------
__global__ void row_nll_kernel(const float* __restrict__ partial_m,
                               const float* __restrict__ partial_s,
                               const float* __restrict__ label_logit,
                               const int* __restrict__ labels,
                               float* __restrict__ nll)
{
    int row = blockIdx.x * blockDim.x + threadIdx.x;
    if (row >= N_) return;
    const float* pm = partial_m + (size_t)row * NVB;
    const float* ps = partial_s + (size_t)row * NVB;
    float mm = -INFINITY;
    for (int j = 0; j < NVB; ++j) mm = fmaxf(mm, pm[j]);
    float ss = 0.f;
    for (int j = 0; j < NVB; ++j) ss += ps[j] * expf(pm[j] - mm);
    float lse = mm + logf(ss);
    int b = row / (S_ - 1);
    int s = row - b * (S_ - 1);
    int lbl = labels[b * S_ + s + 1];
    float out = 0.f;
    if (lbl != IGNORE_INDEX) out = lse - label_logit[row];
    nll[row] = out;
}

// ---------- final mean over valid rows ----------
__global__ void final_reduce_kernel(const float* __restrict__ nll,
                                    const int* __restrict__ labels,
                                    float* __restrict__ out)
{
    __shared__ float s_sum[256];
    __shared__ float s_cnt[256];
    int tid = threadIdx.x;
    float sum = 0.f, cnt = 0.f;
    for (int row = tid; row < N_; row += 256) {
        int b = row / (S_ - 1);
        int s = row - b * (S_ - 1);
        int lbl = labels[b * S_ + s + 1];
        if (lbl != IGNORE_INDEX) { sum += nll[row]; cnt += 1.f; }
    }
    s_sum[tid] = sum; s_cnt[tid] = cnt;
    __syncthreads();
    for (int d = 128; d > 0; d >>= 1) {
        if (tid < d) { s_sum[tid] += s_sum[tid + d]; s_cnt[tid] += s_cnt[tid + d]; }
        __syncthreads();
    }
    if (tid == 0) out[0] = s_sum[0] / fmaxf(s_cnt[0], 1.f);
}

extern "C" void kernel_launch(void* const* d_in, const int* in_sizes, int n_in,
                              void* d_out, int out_size, void* d_ws, size_t ws_size,
                              hipStream_t stream) {
    const float* hs  = (const float*)d_in[0];
    const float* w   = (const float*)d_in[1];
    const int*   lbl = (const int*)d_in[2];
    float* out = (float*)d_out;

    char* ws = (char*)d_ws;
    size_t off = 0;
    signed char* qA = (signed char*)(ws + off); off += (size_t)NPAD * H_;      // 33.5 MB
    signed char* qW = (signed char*)(ws + off); off += (size_t)V_ * H_;        // 131 MB
    float* sA          = (float*)(ws + off); off += (size_t)NPAD * 4;
    float* sW          = (float*)(ws + off); off += (size_t)V_ * 4;
    float* partial_m   = (float*)(ws + off); off += (size_t)NPAD * NVB * 4;    // 4 MB
    float* partial_s   = (float*)(ws + off); off += (size_t)NPAD * NVB * 4;    // 4 MB
    float* label_logit = (float*)(ws + off); off += (size_t)NPAD * 4;
    float* nll         = (float*)(ws + off); off += (size_t)NPAD * 4;

    quant_hs_kernel<<<NPAD, 256, 0, stream>>>(hs, qA, sA);
    quant_w_kernel<<<V_, 256, 0, stream>>>(w, qW, sW);
    gemm_lse_kernel<<<NWG, 512, 0, stream>>>(qA, qW, sA, sW, lbl,
                                             partial_m, partial_s, label_logit);
    row_nll_kernel<<<(N_ + 255) / 256, 256, 0, stream>>>(partial_m, partial_s, label_logit, lbl, nll);
    final_reduce_kernel<<<1, 256, 0, stream>>>(nll, lbl, out);
}